// Round 1
// baseline (130.915 us; speedup 1.0000x reference)
//
#include <hip/hip_runtime.h>

typedef __bf16 bf16_t;
typedef bf16_t bf16x8 __attribute__((ext_vector_type(8)));
typedef float f32x4 __attribute__((ext_vector_type(4)));
typedef unsigned short ushort_t;
typedef unsigned int uint_t;

#define L2E 1.44269504088896340736f
#define NEG_BIG -3.0e38f

// ---------------- fp32 -> bf16 conversion (RNE) ----------------
__device__ inline ushort_t f2bf1(float f) {
    uint_t u = __float_as_uint(f);
    uint_t r = (u + 0x7fffu + ((u >> 16) & 1u)) >> 16;
    return (ushort_t)r;
}

__global__ void f2bf_kernel(const float* __restrict__ in, ushort_t* __restrict__ out) {
    int i = blockIdx.x * blockDim.x + threadIdx.x;   // one float4 per thread
    float4 f = reinterpret_cast<const float4*>(in)[i];
    ushort4 o;
    o.x = f2bf1(f.x); o.y = f2bf1(f.y); o.z = f2bf1(f.z); o.w = f2bf1(f.w);
    reinterpret_cast<ushort4*>(out)[i] = o;
}

// ---------------- label histogram (class counts) ----------------
__global__ void hist_kernel(const int* __restrict__ labels, int* __restrict__ hist) {
    int i = blockIdx.x * blockDim.x + threadIdx.x;
    if (i < 4096) atomicAdd(&hist[labels[i]], 1);
}

// ---------------- main MFMA kernel ----------------
// Grid: (64 row-tiles, 8 column-chunks). Block: 512 threads = 8 waves (2x4).
// Each block: rows r0..r0+127, columns c0..c0+1023 (8 tiles of 128).
// Per-lane online (max, sumexp, same_sum) with defer-max threshold 8.
__global__ __launch_bounds__(512) void supcon_main(
        const ushort_t* __restrict__ Fb,     // 8192 x 256 bf16 (as u16)
        const int* __restrict__ labels,      // 4096 labels
        float* __restrict__ part)            // [8192][32][4] partials (M,S,T,-)
{
    extern __shared__ char lds[];
    char* As = lds;             // 128 x 256 bf16 = 64 KB
    char* Bs = lds + 65536;     // 128 x 256 bf16 = 64 KB

    const int tid  = threadIdx.x;
    const int lane = tid & 63;
    const int wid  = tid >> 6;
    const int wr   = (wid >> 2) * 64;   // wave row offset in 128-tile
    const int wc   = (wid & 3) * 32;    // wave col offset in 128-tile
    const int g    = lane >> 4;         // 4-lane-group id (0..3)
    const int l15  = lane & 15;

    const int r0 = blockIdx.x * 128;    // global row base
    const int c0 = blockIdx.y * 1024;   // global col base (chunk)

    // ---- stage A tile (rows r0..r0+127, all K=256) into LDS, swizzled ----
    #pragma unroll
    for (int it = 0; it < 8; ++it) {
        int c   = it * 512 + tid;           // 16B-chunk id, 0..4095
        int row = c >> 5;                   // 32 chunks per 512B row
        int sl  = c & 31;
        uint4 v = *reinterpret_cast<const uint4*>(Fb + (size_t)(r0 + row) * 256 + sl * 8);
        int addr = row * 512 + sl * 16;
        addr ^= (row & 7) << 4;             // bank swizzle
        *reinterpret_cast<uint4*>(As + addr) = v;
    }

    // ---- per-lane row labels (16 rows this lane reduces) ----
    int labr[16];
    #pragma unroll
    for (int m = 0; m < 4; ++m)
        #pragma unroll
        for (int v = 0; v < 4; ++v) {
            int i = r0 + wr + m * 16 + g * 4 + v;
            labr[m * 4 + v] = labels[i & 4095];
        }

    float M[16], S[16], T[16];
    #pragma unroll
    for (int x = 0; x < 16; ++x) { M[x] = NEG_BIG; S[x] = 0.0f; T[x] = 0.0f; }

    for (int t = 0; t < 8; ++t) {
        const int j0 = c0 + t * 128;
        __syncthreads();   // everyone done reading Bs from previous tile
        // ---- stage B tile (rows j0..j0+127 of F) ----
        #pragma unroll
        for (int it = 0; it < 8; ++it) {
            int c   = it * 512 + tid;
            int row = c >> 5;
            int sl  = c & 31;
            uint4 v = *reinterpret_cast<const uint4*>(Fb + (size_t)(j0 + row) * 256 + sl * 8);
            int addr = row * 512 + sl * 16;
            addr ^= (row & 7) << 4;
            *reinterpret_cast<uint4*>(Bs + addr) = v;
        }
        __syncthreads();

        // ---- compute 64x32 wave sub-tile: acc[m][n], K=256 ----
        f32x4 acc[4][2];
        #pragma unroll
        for (int m = 0; m < 4; ++m)
            #pragma unroll
            for (int n = 0; n < 2; ++n)
                #pragma unroll
                for (int q = 0; q < 4; ++q) acc[m][n][q] = 0.0f;

        #pragma unroll
        for (int kk = 0; kk < 8; ++kk) {
            const int kb = kk * 64 + g * 16;   // byte offset within row
            bf16x8 a[4], b[2];
            #pragma unroll
            for (int m = 0; m < 4; ++m) {
                int row = wr + m * 16 + l15;
                int addr = row * 512 + kb;
                addr ^= (row & 7) << 4;
                a[m] = *reinterpret_cast<const bf16x8*>(As + addr);
            }
            #pragma unroll
            for (int n = 0; n < 2; ++n) {
                int col = wc + n * 16 + l15;
                int addr = col * 512 + kb;
                addr ^= (col & 7) << 4;
                b[n] = *reinterpret_cast<const bf16x8*>(Bs + addr);
            }
            #pragma unroll
            for (int m = 0; m < 4; ++m)
                #pragma unroll
                for (int n = 0; n < 2; ++n)
                    acc[m][n] = __builtin_amdgcn_mfma_f32_16x16x32_bf16(a[m], b[n], acc[m][n], 0, 0, 0);
        }

        // ---- fused epilogue: online softmax + same-label sum ----
        int jc0 = j0 + wc + l15;
        int jc1 = jc0 + 16;
        int labc0 = labels[jc0 & 4095];
        int labc1 = labels[jc1 & 4095];

        #pragma unroll
        for (int m = 0; m < 4; ++m) {
            #pragma unroll
            for (int v = 0; v < 4; ++v) {
                const int idx = m * 4 + v;
                const int i = r0 + wr + m * 16 + g * 4 + v;   // global row
                float x0 = acc[m][0][v] * 10.0f;              // /TEMPERATURE
                float x1 = acc[m][1][v] * 10.0f;
                bool d0 = (jc0 == i), d1 = (jc1 == i);
                if (!d0 && labc0 == labr[idx]) T[idx] += x0;
                if (!d1 && labc1 == labr[idx]) T[idx] += x1;
                if (d0) x0 = NEG_BIG;
                if (d1) x1 = NEG_BIG;
                float tm = fmaxf(x0, x1);
                float Mi = M[idx];
                if (tm > Mi + 8.0f) {                          // defer-max (T13)
                    S[idx] *= exp2f((Mi - tm) * L2E);
                    Mi = tm;
                    M[idx] = tm;
                }
                S[idx] += exp2f((x0 - Mi) * L2E) + exp2f((x1 - Mi) * L2E);
            }
        }
    }

    // ---- cross-lane merge within each 16-lane group ----
    #pragma unroll
    for (int idx = 0; idx < 16; ++idx) {
        float m_ = M[idx], s_ = S[idx], t_ = T[idx];
        #pragma unroll
        for (int d = 1; d < 16; d <<= 1) {
            float mo = __shfl_xor(m_, d, 64);
            float so = __shfl_xor(s_, d, 64);
            float to = __shfl_xor(t_, d, 64);
            float nm = fmaxf(m_, mo);
            s_ = s_ * exp2f((m_ - nm) * L2E) + so * exp2f((mo - nm) * L2E);
            m_ = nm;
            t_ += to;
        }
        M[idx] = m_; S[idx] = s_; T[idx] = t_;
    }

    if (l15 == 0) {
        const int slot = blockIdx.y * 4 + (wid & 3);   // 32 partial slots per row
        #pragma unroll
        for (int idx = 0; idx < 16; ++idx) {
            int m = idx >> 2, v = idx & 3;
            int i = r0 + wr + m * 16 + g * 4 + v;
            float* p = part + ((size_t)i * 32 + slot) * 4;
            p[0] = M[idx]; p[1] = S[idx]; p[2] = T[idx];
        }
    }
}

// ---------------- combine partials -> per-row loss ----------------
__global__ void combine_kernel(const float* __restrict__ part,
                               const int* __restrict__ labels,
                               const int* __restrict__ hist,
                               float* __restrict__ row_loss) {
    int r = blockIdx.x * blockDim.x + threadIdx.x;   // 0..8191
    const float* p = part + (size_t)r * 128;
    float M = NEG_BIG, S = 0.0f, T = 0.0f;
    for (int s = 0; s < 32; ++s) {
        float mo = p[s * 4 + 0];
        float so = p[s * 4 + 1];
        float to = p[s * 4 + 2];
        float nm = fmaxf(M, mo);
        S = S * exp2f((M - nm) * L2E) + so * exp2f((mo - nm) * L2E);
        M = nm;
        T += to;
    }
    float lse = M + logf(S);
    int lab = labels[r & 4095];
    float c = (float)(2 * hist[lab] - 1);
    row_loss[r] = T / c - lse;
}

// ---------------- final mean reduce ----------------
__global__ void final_kernel(const float* __restrict__ row_loss, float* __restrict__ out) {
    __shared__ float sm[256];
    float a = 0.0f;
    for (int r = threadIdx.x; r < 8192; r += 256) a += row_loss[r];
    sm[threadIdx.x] = a;
    __syncthreads();
    for (int s = 128; s > 0; s >>= 1) {
        if (threadIdx.x < s) sm[threadIdx.x] += sm[threadIdx.x + s];
        __syncthreads();
    }
    if (threadIdx.x == 0) out[0] = -0.1f * sm[0] / 8192.0f;
}

extern "C" void kernel_launch(void* const* d_in, const int* in_sizes, int n_in,
                              void* d_out, int out_size, void* d_ws, size_t ws_size,
                              hipStream_t stream) {
    const float* feat  = (const float*)d_in[0];   // 8192 x 256 fp32
    const int* labels  = (const int*)d_in[1];     // 4096 labels
    float* out = (float*)d_out;

    char* ws = (char*)d_ws;
    ushort_t* Fb    = (ushort_t*)ws;                        // 4 MB
    float* part     = (float*)(ws + (4u << 20));            // 4 MB
    int* hist       = (int*)(ws + (8u << 20));              // 4 KB
    float* row_loss = (float*)(ws + (8u << 20) + 4096);     // 32 KB

    hipMemsetAsync(hist, 0, 4096, stream);
    f2bf_kernel<<<2048, 256, 0, stream>>>(feat, Fb);        // 2M floats / 4 per thread
    hist_kernel<<<16, 256, 0, stream>>>(labels, hist);
    dim3 grid(64, 8);
    supcon_main<<<grid, 512, 131072, stream>>>(Fb, labels, part);
    combine_kernel<<<32, 256, 0, stream>>>(part, labels, hist, row_loss);
    final_kernel<<<1, 256, 0, stream>>>(row_loss, out);
}

// Round 2
// 111.124 us; speedup vs baseline: 1.1781x; 1.1781x over previous
//
#include <hip/hip_runtime.h>

typedef __bf16 bf16_t;
typedef bf16_t bf16x8 __attribute__((ext_vector_type(8)));
typedef float f32x4 __attribute__((ext_vector_type(4)));
typedef unsigned short ushort_t;
typedef unsigned int uint_t;

#define C10L2E 14.4269504088896340736f   // 10 * log2(e)  (1/TEMPERATURE * log2 e)
#define LN2    0.69314718055994530942f
#define NEG_BIG -3.0e38f
#define M0     -1.0e30f

__device__ __forceinline__ float fexp2(float x) { return __builtin_amdgcn_exp2f(x); }
__device__ __forceinline__ float flog2(float x) { return __builtin_amdgcn_logf(x); }

#define GLOAD16(g, l) __builtin_amdgcn_global_load_lds( \
    (const __attribute__((address_space(1))) void*)(g), \
    (__attribute__((address_space(3))) void*)(l), 16, 0, 0)

// ---------------- fp32 -> bf16 (RNE) ----------------
__device__ __forceinline__ ushort_t f2bf1(float f) {
    uint_t u = __float_as_uint(f);
    uint_t r = (u + 0x7fffu + ((u >> 16) & 1u)) >> 16;
    return (ushort_t)r;
}

// ---------------- prep: bf16 convert + class sums G + class histogram ----------------
// grid 2048 x 256; thread i handles (row = i>>6, dims = (i&63)*4)
__global__ void prep_kernel(const float* __restrict__ feat, const int* __restrict__ labels,
                            ushort_t* __restrict__ Fb, float* __restrict__ G,
                            int* __restrict__ hist) {
    int i = blockIdx.x * 256 + threadIdx.x;        // 0..524287
    int r = i >> 6;
    int d4 = (i & 63) << 2;
    float4 f = reinterpret_cast<const float4*>(feat)[i];
    ushort4 o;
    o.x = f2bf1(f.x); o.y = f2bf1(f.y); o.z = f2bf1(f.z); o.w = f2bf1(f.w);
    reinterpret_cast<ushort4*>(Fb)[i] = o;
    int lab = labels[r & 4095];
    float* gp = G + (size_t)lab * 256 + d4;
    atomicAdd(gp + 0, f.x); atomicAdd(gp + 1, f.y);
    atomicAdd(gp + 2, f.z); atomicAdd(gp + 3, f.w);
    if (((i & 63) == 0) && r < 4096) atomicAdd(&hist[lab], 1);
}

// ---------------- main MFMA kernel ----------------
// grid (64,8), 512 threads (8 waves 2x4, wave tile 64x32).
// LDS: A full-K 64KB + B double-buffered K-halves 2x32KB = 128KB.
// Layout: 16B "slots"; physical slot = (logical low-4) ^ (row&15) -> conflict-free b128.
// Staged via global_load_lds with pre-swizzled global source (linear LDS dest).
__global__ __launch_bounds__(512, 2) void supcon_main(
        const ushort_t* __restrict__ Fb, float* __restrict__ part) {
    extern __shared__ char lds[];
    char* As = lds;                               // [128 rows][32 slots]
    char* Bbuf0 = lds + 65536;                    // [128 rows][16 slots]
    char* Bbuf1 = lds + 65536 + 32768;

    const int tid  = threadIdx.x;
    const int lane = tid & 63;
    const int wid  = tid >> 6;
    const int wr   = (wid >> 2) * 64;
    const int wc   = (wid & 3) * 32;
    const int g    = lane >> 4;
    const int l15  = lane & 15;
    const int r0 = blockIdx.x * 128;
    const int c0 = blockIdx.y * 1024;

    // ---- stage A once (64KB) ----
    #pragma unroll
    for (int i = 0; i < 8; ++i) {
        int c = (wid * 8 + i) * 64 + lane;        // 16B-chunk id 0..4095
        int row = c >> 5, sl = c & 31;
        int ssrc = (sl & 16) | ((sl ^ row) & 15); // inverse swizzle on SOURCE
        const ushort_t* gp = Fb + (size_t)(r0 + row) * 256 + ssrc * 8;
        GLOAD16(gp, As + (wid * 8 + i) * 1024 + lane * 16);
    }
    // ---- stage B phase 0 (tile 0, k-half 0) ----
    #pragma unroll
    for (int i = 0; i < 4; ++i) {
        int c = (wid * 4 + i) * 64 + lane;        // 0..2047
        int row = c >> 4, sl = c & 15;
        int ssrc = sl ^ (row & 15);
        const ushort_t* gp = Fb + (size_t)(c0 + row) * 256 + ssrc * 8;
        GLOAD16(gp, Bbuf0 + (wid * 4 + i) * 1024 + lane * 16);
    }
    __syncthreads();   // drains vmcnt

    float S[16], ML2[16], MrT[16];
    #pragma unroll
    for (int x = 0; x < 16; ++x) { S[x] = 0.0f; ML2[x] = M0; MrT[x] = M0; }

    f32x4 acc[4][2];

    #pragma unroll 2
    for (int p = 0; p < 16; ++p) {
        const int t = p >> 1, h = p & 1;

        // ---- issue async stage of next phase (lands by the end-of-phase barrier) ----
        if (p < 15) {
            const int pn = p + 1;
            const int j0n = c0 + (pn >> 1) * 128;
            const int hn = pn & 1;
            char* Bd = (pn & 1) ? Bbuf1 : Bbuf0;
            #pragma unroll
            for (int i = 0; i < 4; ++i) {
                int c = (wid * 4 + i) * 64 + lane;
                int row = c >> 4, sl = c & 15;
                int ssrc = sl ^ (row & 15);
                const ushort_t* gp = Fb + (size_t)(j0n + row) * 256 + hn * 128 + ssrc * 8;
                GLOAD16(gp, Bd + (wid * 4 + i) * 1024 + lane * 16);
            }
        }

        if (h == 0) {
            #pragma unroll
            for (int m = 0; m < 4; ++m)
                #pragma unroll
                for (int n = 0; n < 2; ++n)
                    #pragma unroll
                    for (int q = 0; q < 4; ++q) acc[m][n][q] = 0.0f;
        }

        const char* Bp = (p & 1) ? Bbuf1 : Bbuf0;
        #pragma unroll
        for (int kk = 0; kk < 4; ++kk) {
            const int sx = (kk * 4 + g) ^ l15;    // swizzled slot (0..15)
            bf16x8 a[4], b[2];
            #pragma unroll
            for (int m = 0; m < 4; ++m) {
                int row = wr + m * 16 + l15;
                a[m] = *reinterpret_cast<const bf16x8*>(As + row * 512 + (h * 16 + sx) * 16);
            }
            #pragma unroll
            for (int n = 0; n < 2; ++n) {
                int col = wc + n * 16 + l15;
                b[n] = *reinterpret_cast<const bf16x8*>(Bp + col * 256 + sx * 16);
            }
            #pragma unroll
            for (int m = 0; m < 4; ++m)
                #pragma unroll
                for (int n = 0; n < 2; ++n)
                    acc[m][n] = __builtin_amdgcn_mfma_f32_16x16x32_bf16(a[m], b[n], acc[m][n], 0, 0, 0);
        }

        if (h == 1) {
            const int j0 = c0 + t * 128;
            const int jc0 = j0 + wc + l15;
            auto epi = [&](bool DIAG) {
                #pragma unroll
                for (int m = 0; m < 4; ++m) {
                    #pragma unroll
                    for (int v = 0; v < 4; ++v) {
                        const int idx = m * 4 + v;
                        float x0 = acc[m][0][v];
                        float x1 = acc[m][1][v];
                        if (DIAG) {
                            int i = r0 + wr + m * 16 + g * 4 + v;
                            if (jc0 == i) x0 = NEG_BIG;
                            if (jc0 + 16 == i) x1 = NEG_BIG;
                        }
                        float tm = fmaxf(x0, x1);
                        if (tm > MrT[idx]) {               // defer-max (0.8 raw = 8 logit units)
                            float nm = tm * C10L2E;
                            S[idx] *= fexp2(ML2[idx] - nm);
                            ML2[idx] = nm;
                            MrT[idx] = tm + 0.8f;
                        }
                        S[idx] += fexp2(fmaf(x0, C10L2E, -ML2[idx]))
                                + fexp2(fmaf(x1, C10L2E, -ML2[idx]));
                    }
                }
            };
            if (j0 == r0) epi(true); else epi(false);
        }
        __syncthreads();   // drains vmcnt(0): staged loads complete; buffers safe
    }

    // ---- cross-lane merge within 16-lane groups (cols) and store partials ----
    #pragma unroll
    for (int idx = 0; idx < 16; ++idx) {
        float m_ = ML2[idx];
        #pragma unroll
        for (int d = 1; d < 16; d <<= 1) m_ = fmaxf(m_, __shfl_xor(m_, d, 64));
        float s_ = S[idx] * fexp2(ML2[idx] - m_);
        #pragma unroll
        for (int d = 1; d < 16; d <<= 1) s_ += __shfl_xor(s_, d, 64);
        if (l15 == 0) {
            int m = idx >> 2, v = idx & 3;
            int i = r0 + wr + m * 16 + g * 4 + v;
            int slot = blockIdx.y * 4 + (wid & 3);
            float2 val; val.x = m_; val.y = s_;
            *reinterpret_cast<float2*>(part + ((size_t)i * 32 + slot) * 2) = val;
        }
    }
}

// ---------------- combine: merge partials + closed-form T -> per-row loss ----------------
// one wave per row; grid 2048 x 256
__global__ void combine_kernel(const float* __restrict__ feat, const float* __restrict__ G,
                               const int* __restrict__ labels, const int* __restrict__ hist,
                               const float* __restrict__ part, float* __restrict__ row_loss) {
    int r = blockIdx.x * 4 + (threadIdx.x >> 6);
    int lane = threadIdx.x & 63;
    int lab = labels[r & 4095];

    float4 f = reinterpret_cast<const float4*>(feat)[(size_t)r * 64 + lane];
    float4 q = reinterpret_cast<const float4*>(G)[(size_t)lab * 64 + lane];
    float dot = f.x * q.x + f.y * q.y + f.z * q.z + f.w * q.w;
    float nrm = f.x * f.x + f.y * f.y + f.z * f.z + f.w * f.w;
    #pragma unroll
    for (int d = 1; d < 64; d <<= 1) {
        dot += __shfl_xor(dot, d, 64);
        nrm += __shfl_xor(nrm, d, 64);
    }

    float m_ = M0, s_ = 0.0f;
    if (lane < 32) {
        float2 v = reinterpret_cast<const float2*>(part)[(size_t)r * 32 + lane];
        m_ = v.x; s_ = v.y;
    }
    #pragma unroll
    for (int d = 1; d < 32; d <<= 1) {
        float mo = __shfl_xor(m_, d, 64);
        float so = __shfl_xor(s_, d, 64);
        float nm = fmaxf(m_, mo);
        s_ = s_ * fexp2(m_ - nm) + so * fexp2(mo - nm);
        m_ = nm;
    }

    if (lane == 0) {
        float lse = LN2 * (m_ + flog2(s_));        // in logit units
        float T = (dot - nrm) * 10.0f;             // sum of same-label logits (diag removed)
        float c = (float)(2 * hist[lab] - 1);
        row_loss[r] = T / c - lse;
    }
}

// ---------------- final mean reduce ----------------
__global__ void final_kernel(const float* __restrict__ row_loss, float* __restrict__ out) {
    __shared__ float sm[256];
    float a = 0.0f;
    for (int r = threadIdx.x; r < 8192; r += 256) a += row_loss[r];
    sm[threadIdx.x] = a;
    __syncthreads();
    for (int s = 128; s > 0; s >>= 1) {
        if (threadIdx.x < s) sm[threadIdx.x] += sm[threadIdx.x + s];
        __syncthreads();
    }
    if (threadIdx.x == 0) out[0] = -0.1f * sm[0] / 8192.0f;
}

extern "C" void kernel_launch(void* const* d_in, const int* in_sizes, int n_in,
                              void* d_out, int out_size, void* d_ws, size_t ws_size,
                              hipStream_t stream) {
    const float* feat = (const float*)d_in[0];    // 8192 x 256 fp32
    const int* labels = (const int*)d_in[1];      // 4096
    float* out = (float*)d_out;

    char* ws = (char*)d_ws;
    ushort_t* Fb    = (ushort_t*)ws;                        // 4 MB
    float* part     = (float*)(ws + (4u << 20));            // 2 MB
    float* G        = (float*)(ws + (6u << 20));            // 1 MB
    int* hist       = (int*)(ws + (7u << 20));              // 4 KB
    float* row_loss = (float*)(ws + (7u << 20) + 4096);     // 32 KB

    hipMemsetAsync(ws + (6u << 20), 0, (1u << 20) + 4096, stream);   // G + hist
    prep_kernel<<<2048, 256, 0, stream>>>(feat, labels, Fb, G, hist);
    dim3 grid(64, 8);
    supcon_main<<<grid, 512, 131072, stream>>>(Fb, part);
    combine_kernel<<<2048, 256, 0, stream>>>(feat, G, labels, hist, part, row_loss);
    final_kernel<<<1, 256, 0, stream>>>(row_loss, out);
}

// Round 3
// 69.646 us; speedup vs baseline: 1.8797x; 1.5956x over previous
//
#include <hip/hip_runtime.h>

typedef __bf16 bf16_t;
typedef bf16_t bf16x8 __attribute__((ext_vector_type(8)));
typedef float f32x4 __attribute__((ext_vector_type(4)));
typedef unsigned short ushort_t;
typedef unsigned int uint_t;

#define C10L2E 14.4269504088896340736f   // 10 * log2(e)
#define LN2    0.69314718055994530942f
#define NEG_BIG -3.0e38f
#define M0     -1.0e30f
#define THR_L2 11.5415603f               // 0.8 raw logit units in log2-space

static __device__ __forceinline__ float fexp2(float x){ return __builtin_amdgcn_exp2f(x); }
static __device__ __forceinline__ float flog2(float x){ return __builtin_amdgcn_logf(x); }

#define GLOAD16(g, l) __builtin_amdgcn_global_load_lds( \
    (const __attribute__((address_space(1))) void*)(g), \
    (__attribute__((address_space(3))) void*)(l), 16, 0, 0)

// ---------------- fp32 -> bf16 (RNE) ----------------
static __device__ __forceinline__ ushort_t f2bf1(float f) {
    uint_t u = __float_as_uint(f);
    uint_t r = (u + 0x7fffu + ((u >> 16) & 1u)) >> 16;
    return (ushort_t)r;
}

__global__ void prep_kernel(const float* __restrict__ feat, ushort_t* __restrict__ Fb) {
    int i = blockIdx.x * 256 + threadIdx.x;        // 0..524287 float4s
    float4 f = reinterpret_cast<const float4*>(feat)[i];
    ushort4 o;
    o.x = f2bf1(f.x); o.y = f2bf1(f.y); o.z = f2bf1(f.z); o.w = f2bf1(f.w);
    reinterpret_cast<ushort4*>(Fb)[i] = o;
}

// ---------------- label scatter: per-class counts + row index lists ----------------
__global__ void scatter_kernel(const int* __restrict__ labels, int* __restrict__ cnt,
                               int* __restrict__ idxl) {
    int i = blockIdx.x * 256 + threadIdx.x;
    if (i < 4096) {
        int lab = labels[i];
        int p = atomicAdd(&cnt[lab], 1);
        if (p < 64) idxl[lab * 64 + p] = i;
    }
}

// ---------------- per-class term: (|G_c|^2 - sum|f_i|^2) / (2*cnt-1) ----------------
// one wave per class; lane = dim/4
__global__ void classterm_kernel(const float* __restrict__ feat, const int* __restrict__ cnt,
                                 const int* __restrict__ idxl, float* __restrict__ term) {
    int c = blockIdx.x;
    int lane = threadIdx.x;                         // 0..63
    int n = cnt[c];
    float4 g4 = make_float4(0.f, 0.f, 0.f, 0.f);
    float n2 = 0.f;
    for (int e = 0; e < n; ++e) {
        int r = idxl[c * 64 + e];
        float4 f0 = reinterpret_cast<const float4*>(feat)[(size_t)r * 64 + lane];
        float4 f1 = reinterpret_cast<const float4*>(feat)[(size_t)(r + 4096) * 64 + lane];
        g4.x += f0.x + f1.x; g4.y += f0.y + f1.y;
        g4.z += f0.z + f1.z; g4.w += f0.w + f1.w;
        n2 += f0.x*f0.x + f0.y*f0.y + f0.z*f0.z + f0.w*f0.w
            + f1.x*f1.x + f1.y*f1.y + f1.z*f1.z + f1.w*f1.w;
    }
    float gg = g4.x*g4.x + g4.y*g4.y + g4.z*g4.z + g4.w*g4.w;
    #pragma unroll
    for (int d = 1; d < 64; d <<= 1) {
        gg += __shfl_xor(gg, d, 64);
        n2 += __shfl_xor(n2, d, 64);
    }
    if (lane == 0) term[c] = (n > 0) ? (gg - n2) / (float)(2 * n - 1) : 0.0f;
}

// ---------------- main MFMA kernel ----------------
// grid (64,4): 256 blocks = 1/CU. 512 threads = 8 waves (2 row-groups x 4 col-groups),
// wave tile 64x64 (acc 4x4 of 16x16). Block tile 128 rows x 256 cols; each block
// sweeps 8 col-tiles x 4 K-quarters = 32 phases.
// LDS 128KB: A full-K (128x256bf16=64KB) + B double-buffered K-quarter (256x64=32KB x2).
// 16B-slot XOR swizzles; staging via global_load_lds with pre-swizzled source.
__global__ __launch_bounds__(512, 2) void supcon_main(
        const ushort_t* __restrict__ Fb, float* __restrict__ part) {
    extern __shared__ char lds[];
    char* As = lds;                                  // [128][32 slots]
    char* Bb0 = lds + 65536;                         // [256][8 slots]
    char* Bb1 = lds + 65536 + 32768;

    const int tid  = threadIdx.x;
    const int lane = tid & 63;
    const int wid  = tid >> 6;
    const int wr   = (wid >> 2) * 64;
    const int wc   = (wid & 3) * 64;
    const int g    = lane >> 4;
    const int l15  = lane & 15;
    const int r0 = blockIdx.x * 128;
    const int c0 = blockIdx.y * 2048;

    // ---- stage A once ----
    #pragma unroll
    for (int i = 0; i < 8; ++i) {
        int c = (wid * 8 + i) * 64 + lane;          // 0..4095
        int row = c >> 5, sl = c & 31;
        int lslot = (sl & 16) | ((sl ^ row) & 15);
        GLOAD16(Fb + (size_t)(r0 + row) * 256 + lslot * 8, As + c * 16);
    }
    // ---- precompute B staging geometry (per thread, 4 chunks) ----
    int bgofs[4], bdst[4];
    #pragma unroll
    for (int i = 0; i < 4; ++i) {
        int c = (wid * 4 + i) * 64 + lane;          // 0..2047
        int col = c >> 3, ps = c & 7;
        int lslot = ps ^ (col & 7);
        bgofs[i] = col * 256 + lslot * 8;           // element offset within a col-tile
        bdst[i] = c * 16;
    }
    // ---- stage B phase 0 ----
    #pragma unroll
    for (int i = 0; i < 4; ++i)
        GLOAD16(Fb + (size_t)c0 * 256 + bgofs[i], Bb0 + bdst[i]);
    __syncthreads();

    float ML2[16], S[16];
    #pragma unroll
    for (int x = 0; x < 16; ++x) { ML2[x] = M0; S[x] = 0.0f; }

    f32x4 acc[4][4];

    auto stage_next = [&](int pn) {
        int j0n = c0 + (pn >> 2) * 256;
        int qn = pn & 3;
        char* Bd = (pn & 1) ? Bb1 : Bb0;
        #pragma unroll
        for (int i = 0; i < 4; ++i)
            GLOAD16(Fb + (size_t)j0n * 256 + qn * 64 + bgofs[i], Bd + bdst[i]);
    };

    auto do_phase = [&](int p, bool ZERO, bool EPI) {
        if (p < 31) stage_next(p + 1);
        if (ZERO) {
            #pragma unroll
            for (int m = 0; m < 4; ++m)
                #pragma unroll
                for (int n = 0; n < 4; ++n)
                    #pragma unroll
                    for (int q_ = 0; q_ < 4; ++q_) acc[m][n][q_] = 0.0f;
        }
        const char* Bp = (p & 1) ? Bb1 : Bb0;
        const int q = p & 3;
        #pragma unroll
        for (int kk = 0; kk < 2; ++kk) {
            int sA = q * 8 + kk * 4 + g;
            int pA = (sA & 16) | ((sA ^ l15) & 15);
            bf16x8 a[4], b[4];
            #pragma unroll
            for (int m = 0; m < 4; ++m)
                a[m] = *reinterpret_cast<const bf16x8*>(As + (wr + m * 16 + l15) * 512 + pA * 16);
            int pB = (kk * 4 + g) ^ (l15 & 7);
            #pragma unroll
            for (int n = 0; n < 4; ++n)
                b[n] = *reinterpret_cast<const bf16x8*>(Bp + (wc + n * 16 + l15) * 128 + pB * 16);
            #pragma unroll
            for (int m = 0; m < 4; ++m)
                #pragma unroll
                for (int n = 0; n < 4; ++n)
                    acc[m][n] = __builtin_amdgcn_mfma_f32_16x16x32_bf16(a[m], b[n], acc[m][n], 0, 0, 0);
        }
        if (EPI) {
            const int j0 = c0 + (p >> 2) * 256;
            const bool diag = (j0 == (r0 & ~255));
            const int jc = j0 + wc + l15;
            #pragma unroll
            for (int m = 0; m < 4; ++m) {
                #pragma unroll
                for (int v = 0; v < 4; ++v) {
                    const int idx = m * 4 + v;
                    float x0 = acc[m][0][v], x1 = acc[m][1][v];
                    float x2 = acc[m][2][v], x3 = acc[m][3][v];
                    if (diag) {
                        int i = r0 + wr + m * 16 + g * 4 + v;
                        if (jc      == i) x0 = NEG_BIG;
                        if (jc + 16 == i) x1 = NEG_BIG;
                        if (jc + 32 == i) x2 = NEG_BIG;
                        if (jc + 48 == i) x3 = NEG_BIG;
                    }
                    float tm = fmaxf(fmaxf(x0, x1), fmaxf(x2, x3));
                    float cc = tm * C10L2E;
                    float ml = ML2[idx];
                    if (cc > ml + THR_L2) {          // rare rescale (defer-max)
                        S[idx] *= fexp2(ml - cc);
                        ml = cc;
                        ML2[idx] = cc;
                    }
                    S[idx] += fexp2(fmaf(x0, C10L2E, -ml)) + fexp2(fmaf(x1, C10L2E, -ml))
                            + fexp2(fmaf(x2, C10L2E, -ml)) + fexp2(fmaf(x3, C10L2E, -ml));
                }
            }
        }
        __syncthreads();
    };

    for (int t = 0; t < 8; ++t) {
        do_phase(t * 4 + 0, true,  false);
        do_phase(t * 4 + 1, false, false);
        do_phase(t * 4 + 2, false, false);
        do_phase(t * 4 + 3, false, true);
    }

    // ---- cross-lane merge within 16-lane groups, store partials ----
    const int slot = blockIdx.y * 4 + (wid & 3);
    #pragma unroll
    for (int idx = 0; idx < 16; ++idx) {
        float m_ = ML2[idx], s_ = S[idx];
        #pragma unroll
        for (int d = 1; d < 16; d <<= 1) {
            float mo = __shfl_xor(m_, d, 64);
            float so = __shfl_xor(s_, d, 64);
            float nm = fmaxf(m_, mo);
            s_ = s_ * fexp2(m_ - nm) + so * fexp2(mo - nm);
            m_ = nm;
        }
        if (l15 == 0) {
            int i = r0 + wr + (idx >> 2) * 16 + g * 4 + (idx & 3);
            float2 val; val.x = m_; val.y = s_;
            *reinterpret_cast<float2*>(part + ((size_t)i * 16 + slot) * 2) = val;
        }
    }
}

// ---------------- combine: merge 16 partials/row -> lse, block-sum ----------------
// 256 threads = 16 quarter-waves = 16 rows per block; grid 512
__global__ void combine_kernel(const float* __restrict__ part, float* __restrict__ blk_lse) {
    __shared__ float sm[16];
    int tid = threadIdx.x;
    int row = blockIdx.x * 16 + (tid >> 4);
    int l16 = tid & 15;
    float2 v = reinterpret_cast<const float2*>(part)[(size_t)row * 16 + l16];
    float m_ = v.x, s_ = v.y;
    #pragma unroll
    for (int d = 1; d < 16; d <<= 1) {
        float mo = __shfl_xor(m_, d, 64);
        float so = __shfl_xor(s_, d, 64);
        float nm = fmaxf(m_, mo);
        s_ = s_ * fexp2(m_ - nm) + so * fexp2(mo - nm);
        m_ = nm;
    }
    if (l16 == 0) sm[tid >> 4] = LN2 * (m_ + flog2(s_));
    __syncthreads();
    if (tid == 0) {
        float a = 0.f;
        #pragma unroll
        for (int i = 0; i < 16; ++i) a += sm[i];
        blk_lse[blockIdx.x] = a;
    }
}

// ---------------- final: loss = 0.1/8192 * (sum lse - 10 * sum term) ----------------
__global__ void final_kernel(const float* __restrict__ blk_lse, const float* __restrict__ term,
                             float* __restrict__ out) {
    __shared__ float sm[256];
    int tid = threadIdx.x;
    float a = 0.f;
    for (int i = tid; i < 512; i += 256) a += blk_lse[i];
    for (int i = tid; i < 1000; i += 256) a -= 10.0f * term[i];
    sm[tid] = a;
    __syncthreads();
    for (int s = 128; s > 0; s >>= 1) {
        if (tid < s) sm[tid] += sm[tid + s];
        __syncthreads();
    }
    if (tid == 0) out[0] = sm[0] * (0.1f / 8192.0f);
}

extern "C" void kernel_launch(void* const* d_in, const int* in_sizes, int n_in,
                              void* d_out, int out_size, void* d_ws, size_t ws_size,
                              hipStream_t stream) {
    const float* feat = (const float*)d_in[0];    // 8192 x 256 fp32
    const int* labels = (const int*)d_in[1];      // 4096
    float* out = (float*)d_out;

    char* ws = (char*)d_ws;
    ushort_t* Fb   = (ushort_t*)ws;                                 // 4 MB
    float* part    = (float*)(ws + (4u << 20));                     // 1 MB
    int* cnt       = (int*)(ws + (5u << 20));                       // 4 KB
    int* idxl      = (int*)(ws + (5u << 20) + 4096);                // 256 KB
    float* term    = (float*)(ws + (5u << 20) + 4096 + 262144);     // 4 KB
    float* blk_lse = (float*)(ws + (5u << 20) + 4096 + 262144 + 4096); // 2 KB

    hipMemsetAsync(cnt, 0, 4096, stream);
    prep_kernel<<<2048, 256, 0, stream>>>(feat, Fb);
    scatter_kernel<<<16, 256, 0, stream>>>(labels, cnt, idxl);
    classterm_kernel<<<1000, 64, 0, stream>>>(feat, cnt, idxl, term);
    dim3 grid(64, 4);
    supcon_main<<<grid, 512, 131072, stream>>>(Fb, part);
    combine_kernel<<<512, 256, 0, stream>>>(part, blk_lse);
    final_kernel<<<1, 256, 0, stream>>>(blk_lse, term, out);
}